// Round 1
// baseline (107.212 us; speedup 1.0000x reference)
//
#include <hip/hip_runtime.h>

// FusionLoss: B=256, K=16, H=W=256 (HW=65536).
// One block of 256 threads; thread b handles sample b entirely in registers.
// All loops over K=16 and the 12 edges are fully unrolled so per-thread
// arrays (pred/tgt/x/y/l) live in VGPRs with static indexing.

#define B_   256
#define K_   16
#define HW_  65536

__global__ __launch_bounds__(256, 1)
void FusionLoss_kernel(const float* __restrict__ output,
                       const int*   __restrict__ mask,
                       const int*   __restrict__ ind,
                       const float* __restrict__ target,
                       const float* __restrict__ gt2d,
                       float*       __restrict__ out) {
    const int b = threadIdx.x;   // one sample per thread, 256 threads

    // ---- gather pred, read target/mask; smooth-L1 ----
    float pred[K_], tgt[K_];
    float sl1 = 0.0f;
    float num = 0.0f;
    int   msum = 0;
    #pragma unroll
    for (int k = 0; k < K_; ++k) {
        const int idx = ind[b * K_ + k];
        const float p = output[b * HW_ + idx];
        const float t = target[b * K_ + k];
        pred[k] = p;
        tgt[k]  = t;
        const int mk = mask[b * K_ + k];
        msum += mk;
        if (mk) {
            const float ad = fabsf(p - t);
            sl1 += (ad < 1.0f) ? 0.5f * ad * ad : (ad - 0.5f);
            num += 1.0f;
        }
    }

    // ---- 2D keypoints ----
    float x[K_], y[K_];
    #pragma unroll
    for (int j = 0; j < K_; ++j) {
        x[j] = gt2d[b * 2 * K_ + 2 * j];
        y[j] = gt2d[b * 2 * K_ + 2 * j + 1];
    }

    // ---- 12 edges: lengths, visibility, per-group sums ----
    const int   id1[12] = {0, 1, 3, 4, 10, 11, 13, 14, 2, 3, 12, 13};
    const int   id2[12] = {1, 2, 4, 5, 11, 12, 14, 15, 6, 6,  8,  8};
    const float wgt[12] = {1.0085885098415446f, 1.0f, 1.0f, 1.0085885098415446f,
                           1.1375361376887123f, 1.0f, 1.0f, 1.1375361376887123f,
                           1.0f, 1.0f, 1.0f, 1.0f};
    const int   gid[12] = {0, 0, 0, 0, 1, 1, 1, 1, 2, 2, 3, 3};

    float l[12];
    bool  vis[12];
    float num_g[4] = {0.f, 0.f, 0.f, 0.f};
    float sum_g[4] = {0.f, 0.f, 0.f, 0.f};
    #pragma unroll
    for (int e = 0; e < 12; ++e) {
        const int i1 = id1[e], i2 = id2[e];
        const float dx = x[i1] - x[i2];
        const float dy = y[i1] - y[i2];
        const float dz = pred[i1] - pred[i2];
        const float le = sqrtf(dx * dx + dy * dy + dz * dz) * wgt[e];
        l[e] = le;
        const bool v = (tgt[i1] > 0.5f) && (tgt[i2] > 0.5f);
        vis[e] = v;
        if (v) {
            num_g[gid[e]] += 1.0f;
            sum_g[gid[e]] += le;
        }
    }

    float E[4], ng4[4];
    #pragma unroll
    for (int g = 0; g < 4; ++g) {
        const float n = num_g[g];
        ng4[g] = fmaxf(n, 1.0f);
        E[g]   = (n > 0.5f) ? (sum_g[g] / ng4[g]) : 0.0f;
    }

    float per = 0.0f;
    #pragma unroll
    for (int e = 0; e < 12; ++e) {
        if (vis[e] && (l[e] > 0.0f)) {
            const float d = l[e] - E[gid[e]];
            per += d * d / (2.0f * ng4[gid[e]]);
        }
    }
    float var_c = (msum == 0) ? per : 0.0f;

    // ---- block reduction: sl1, num, var_c ----
    #pragma unroll
    for (int off = 32; off > 0; off >>= 1) {
        sl1   += __shfl_down(sl1,   off);
        num   += __shfl_down(num,   off);
        var_c += __shfl_down(var_c, off);
    }
    __shared__ float s_sl1[4], s_num[4], s_var[4];
    const int wave = threadIdx.x >> 6;
    const int lane = threadIdx.x & 63;
    if (lane == 0) {
        s_sl1[wave] = sl1;
        s_num[wave] = num;
        s_var[wave] = var_c;
    }
    __syncthreads();
    if (threadIdx.x == 0) {
        float tsl1 = 0.f, tnum = 0.f, tvar = 0.f;
        #pragma unroll
        for (int w = 0; w < 4; ++w) {
            tsl1 += s_sl1[w];
            tnum += s_num[w];
            tvar += s_var[w];
        }
        const float reg = tsl1 / (tnum + 0.0001f);
        const float var = tvar / (float)B_;
        out[0] = 1.0f * reg + 0.01f * var;
    }
}

extern "C" void kernel_launch(void* const* d_in, const int* in_sizes, int n_in,
                              void* d_out, int out_size, void* d_ws, size_t ws_size,
                              hipStream_t stream) {
    const float* output = (const float*)d_in[0];  // (256,1,256,256) f32
    const int*   mask   = (const int*)  d_in[1];  // (256,16) i32
    const int*   ind    = (const int*)  d_in[2];  // (256,16) i32
    const float* target = (const float*)d_in[3];  // (256,16,1) f32
    const float* gt2d   = (const float*)d_in[4];  // (256,32) f32
    float* out = (float*)d_out;                   // scalar f32

    FusionLoss_kernel<<<1, 256, 0, stream>>>(output, mask, ind, target, gt2d, out);
}

// Round 2
// 96.084 us; speedup vs baseline: 1.1158x; 1.1158x over previous
//
#include <hip/hip_runtime.h>

// FusionLoss: B=256, K=16, HW=65536.
// Kernel 1: one block per sample (256 blocks x 64 threads). Lanes 0..15
//   gather pred/target/mask in parallel (the latency-bound part), share via
//   LDS, wave-reduce smooth-L1, lane 0 computes the 12-edge variance term
//   serially (~200 cycles), writes one float4 partial per block.
// Kernel 2: one block of 256 threads reduces the 256 partials (L2-hot) and
//   writes the scalar loss.

#define B_   256
#define K_   16
#define HW_  65536

__global__ __launch_bounds__(64, 8)
void fusion_partial(const float* __restrict__ output,
                    const int*   __restrict__ mask,
                    const int*   __restrict__ ind,
                    const float* __restrict__ target,
                    const float* __restrict__ gt2d,
                    float4*      __restrict__ partial) {
    const int b    = blockIdx.x;
    const int lane = threadIdx.x;   // 0..63, single wave

    __shared__ float s_pred[K_];
    __shared__ float s_tgt[K_];
    __shared__ float s_xy[2 * K_];

    float psl1 = 0.0f, pnum = 0.0f;
    int   pm   = 0;

    if (lane < 2 * K_) s_xy[lane] = gt2d[b * 2 * K_ + lane];
    if (lane < K_) {
        const int   idx = ind[b * K_ + lane];
        const float p   = output[b * HW_ + idx];
        const float t   = target[b * K_ + lane];
        const int   mk  = mask[b * K_ + lane];
        s_pred[lane] = p;
        s_tgt[lane]  = t;
        pm = mk;
        if (mk) {
            const float ad = fabsf(p - t);
            psl1 = (ad < 1.0f) ? 0.5f * ad * ad : (ad - 0.5f);
            pnum = 1.0f;
        }
    }

    // 16-lane tree reduce (lanes 16..31 hold zeros)
    #pragma unroll
    for (int off = 8; off > 0; off >>= 1) {
        psl1 += __shfl_down(psl1, off);
        pnum += __shfl_down(pnum, off);
        pm   += __shfl_down(pm,   off);
    }

    __syncthreads();   // drain LDS writes (single wave: cheap)

    if (lane == 0) {
        const int   id1[12] = {0, 1, 3, 4, 10, 11, 13, 14, 2, 3, 12, 13};
        const int   id2[12] = {1, 2, 4, 5, 11, 12, 14, 15, 6, 6,  8,  8};
        const float wgt[12] = {1.0085885098415446f, 1.0f, 1.0f, 1.0085885098415446f,
                               1.1375361376887123f, 1.0f, 1.0f, 1.1375361376887123f,
                               1.0f, 1.0f, 1.0f, 1.0f};
        const int   gid[12] = {0, 0, 0, 0, 1, 1, 1, 1, 2, 2, 3, 3};

        float l[12];
        bool  vis[12];
        float num_g[4] = {0.f, 0.f, 0.f, 0.f};
        float sum_g[4] = {0.f, 0.f, 0.f, 0.f};
        #pragma unroll
        for (int e = 0; e < 12; ++e) {
            const int i1 = id1[e], i2 = id2[e];
            const float dx = s_xy[2 * i1]     - s_xy[2 * i2];
            const float dy = s_xy[2 * i1 + 1] - s_xy[2 * i2 + 1];
            const float dz = s_pred[i1] - s_pred[i2];
            const float le = sqrtf(dx * dx + dy * dy + dz * dz) * wgt[e];
            l[e] = le;
            const bool v = (s_tgt[i1] > 0.5f) && (s_tgt[i2] > 0.5f);
            vis[e] = v;
            if (v) {
                num_g[gid[e]] += 1.0f;
                sum_g[gid[e]] += le;
            }
        }

        float E[4], ng4[4];
        #pragma unroll
        for (int g = 0; g < 4; ++g) {
            const float n = num_g[g];
            ng4[g] = fmaxf(n, 1.0f);
            E[g]   = (n > 0.5f) ? (sum_g[g] / ng4[g]) : 0.0f;
        }

        float per = 0.0f;
        #pragma unroll
        for (int e = 0; e < 12; ++e) {
            if (vis[e] && (l[e] > 0.0f)) {
                const float d = l[e] - E[gid[e]];
                per += d * d / (2.0f * ng4[gid[e]]);
            }
        }
        const float var_c = (pm == 0) ? per : 0.0f;

        partial[b] = make_float4(psl1, pnum, var_c, 0.0f);
    }
}

__global__ __launch_bounds__(256, 1)
void fusion_final(const float4* __restrict__ partial,
                  float*        __restrict__ out) {
    const int t = threadIdx.x;   // 0..255, one per sample
    const float4 v = partial[t];
    float sl1 = v.x, num = v.y, var = v.z;

    #pragma unroll
    for (int off = 32; off > 0; off >>= 1) {
        sl1 += __shfl_down(sl1, off);
        num += __shfl_down(num, off);
        var += __shfl_down(var, off);
    }
    __shared__ float s_sl1[4], s_num[4], s_var[4];
    const int wave = t >> 6;
    const int lane = t & 63;
    if (lane == 0) {
        s_sl1[wave] = sl1;
        s_num[wave] = num;
        s_var[wave] = var;
    }
    __syncthreads();
    if (t == 0) {
        float tsl1 = 0.f, tnum = 0.f, tvar = 0.f;
        #pragma unroll
        for (int w = 0; w < 4; ++w) {
            tsl1 += s_sl1[w];
            tnum += s_num[w];
            tvar += s_var[w];
        }
        out[0] = tsl1 / (tnum + 0.0001f) + 0.01f * (tvar / (float)B_);
    }
}

extern "C" void kernel_launch(void* const* d_in, const int* in_sizes, int n_in,
                              void* d_out, int out_size, void* d_ws, size_t ws_size,
                              hipStream_t stream) {
    const float* output = (const float*)d_in[0];  // (256,1,256,256) f32
    const int*   mask   = (const int*)  d_in[1];  // (256,16) i32
    const int*   ind    = (const int*)  d_in[2];  // (256,16) i32
    const float* target = (const float*)d_in[3];  // (256,16,1) f32
    const float* gt2d   = (const float*)d_in[4];  // (256,32) f32
    float*  out     = (float*)d_out;              // scalar f32
    float4* partial = (float4*)d_ws;              // 256 * 16 B = 4 KiB

    fusion_partial<<<B_, 64, 0, stream>>>(output, mask, ind, target, gt2d, partial);
    fusion_final<<<1, 256, 0, stream>>>(partial, out);
}